// Round 1
// 318.992 us; speedup vs baseline: 1.0402x; 1.0402x over previous
//
#include <hip/hip_runtime.h>

// EquivariantLayerNorm: per row n (65536 rows), x = in[n] (3x256 fp32),
//   mean-center over D; B = x x^T / D + EPS*diag(2,3,4); out = B^{-1/2} x_c * w.
// B^{-1/2} via trace-normalized coupled Newton-Schulz (8 iters, fp32).
//
// R3 layout: 32 lanes per row (8 rows per block of 256). Lane owns 8 columns
// via col = lane_in*4 + j*128 (j=0..1) -> each (v,j) access is 32 consecutive
// float4s = 512 B contiguous per row-group, fully coalesced.
// vs R2 (16 lanes/row): live input footprint halves (48->24 VGPRs across the
// Newton-Schulz chain) -> higher occupancy / 2x TLP for latency hiding on this
// pure-streaming kernel. Loads/stores are nontemporal: both 192 MiB streams
// are touch-once, keep them out of L2/LLC.

namespace {

constexpr int kD = 256;
constexpr float kEps = 1e-3f;
constexpr int kNSIters = 8;

typedef float f4 __attribute__((ext_vector_type(4)));

// Symmetric 3x3 stored as {a00,a01,a02,a11,a12,a22}. P = M*N upper triangle
// (M,N commute up to rounding, so P is symmetric to fp32 noise).
__device__ __forceinline__ void symmul(const float* M, const float* N, float* P) {
    P[0] = M[0]*N[0] + M[1]*N[1] + M[2]*N[2];
    P[1] = M[0]*N[1] + M[1]*N[3] + M[2]*N[4];
    P[2] = M[0]*N[2] + M[1]*N[4] + M[2]*N[5];
    P[3] = M[1]*N[1] + M[3]*N[3] + M[4]*N[4];
    P[4] = M[1]*N[2] + M[3]*N[4] + M[4]*N[5];
    P[5] = M[2]*N[2] + M[4]*N[4] + M[5]*N[5];
}

__global__ __launch_bounds__(256) void eqln_kernel(const float* __restrict__ in,
                                                   const float* __restrict__ wptr,
                                                   float* __restrict__ out,
                                                   int nrows) {
    const int tid     = threadIdx.x;
    const int lane_in = tid & 31;                        // lane within row-group
    const int row     = blockIdx.x * (blockDim.x >> 5) + (tid >> 5);
    if (row >= nrows) return;

    const size_t base = (size_t)row * (3 * kD);
    const int coff = lane_in * 4;                        // + j*128 per block j

    // Load this lane's 8 columns of all 3 rows (24 floats in registers).
    f4 x[3][2];
    #pragma unroll
    for (int v = 0; v < 3; ++v)
        #pragma unroll
        for (int j = 0; j < 2; ++j)
            x[v][j] = __builtin_nontemporal_load(
                (const f4*)(in + base + v * kD + j * 128 + coff));

    // Single-pass raw sums: S_v and Gram Q_uv (9 partials per lane).
    float s[9] = {0.f, 0.f, 0.f, 0.f, 0.f, 0.f, 0.f, 0.f, 0.f};
    #pragma unroll
    for (int j = 0; j < 2; ++j) {
        const f4 a = x[0][j];
        const f4 b = x[1][j];
        const f4 c = x[2][j];
        #pragma unroll
        for (int k = 0; k < 4; ++k) {
            s[0] += a[k];      s[1] += b[k];      s[2] += c[k];
            s[3] += a[k]*a[k]; s[4] += a[k]*b[k]; s[5] += a[k]*c[k];
            s[6] += b[k]*b[k]; s[7] += b[k]*c[k]; s[8] += c[k]*c[k];
        }
    }

    // Butterfly over the 32-lane group (xor offsets stay inside the group).
    #pragma unroll
    for (int off = 16; off > 0; off >>= 1) {
        #pragma unroll
        for (int i = 0; i < 9; ++i) s[i] += __shfl_xor(s[i], off, 64);
    }

    const float inv_d = 1.0f / (float)kD;
    const float m0 = s[0] * inv_d, m1 = s[1] * inv_d, m2 = s[2] * inv_d;

    // B = Q/D - m m^T + EPS*diag(2,3,4)
    float B[6];
    B[0] = s[3] * inv_d - m0 * m0 + 2.0f * kEps;
    B[1] = s[4] * inv_d - m0 * m1;
    B[2] = s[5] * inv_d - m0 * m2;
    B[3] = s[6] * inv_d - m1 * m1 + 3.0f * kEps;
    B[4] = s[7] * inv_d - m1 * m2;
    B[5] = s[8] * inv_d - m2 * m2 + 4.0f * kEps;

    // Coupled Newton-Schulz for A^{-1/2}, A = B / tr(B) (eigenvalues in (0,1]).
    const float tr  = B[0] + B[3] + B[5];
    const float itr = 1.0f / tr;
    float Y[6] = {B[0]*itr, B[1]*itr, B[2]*itr, B[3]*itr, B[4]*itr, B[5]*itr};
    float Z[6] = {1.0f, 0.0f, 0.0f, 1.0f, 0.0f, 1.0f};

    #pragma unroll
    for (int it = 0; it < kNSIters; ++it) {
        float W[6], T[6], Yn[6], Zn[6];
        symmul(Z, Y, W);
        T[0] = 1.5f - 0.5f * W[0];
        T[1] = -0.5f * W[1];
        T[2] = -0.5f * W[2];
        T[3] = 1.5f - 0.5f * W[3];
        T[4] = -0.5f * W[4];
        T[5] = 1.5f - 0.5f * W[5];
        symmul(Y, T, Yn);
        symmul(T, Z, Zn);
        #pragma unroll
        for (int i = 0; i < 6; ++i) { Y[i] = Yn[i]; Z[i] = Zn[i]; }
    }

    // B^{-1/2} = Z / sqrt(tr)
    const float sc  = 1.0f / sqrtf(tr);
    const float M00 = Z[0] * sc, M01 = Z[1] * sc, M02 = Z[2] * sc;
    const float M11 = Z[3] * sc, M12 = Z[4] * sc, M22 = Z[5] * sc;

    // out = M @ (x - m) * weight on this lane's 8 columns.
    #pragma unroll
    for (int j = 0; j < 2; ++j) {
        const f4 wv = *(const f4*)(wptr + j * 128 + coff);
        const f4 a  = x[0][j];
        const f4 b  = x[1][j];
        const f4 c  = x[2][j];
        f4 r0, r1, r2;
        #pragma unroll
        for (int k = 0; k < 4; ++k) {
            const float a0 = a[k] - m0;
            const float a1 = b[k] - m1;
            const float a2 = c[k] - m2;
            r0[k] = (M00 * a0 + M01 * a1 + M02 * a2) * wv[k];
            r1[k] = (M01 * a0 + M11 * a1 + M12 * a2) * wv[k];
            r2[k] = (M02 * a0 + M12 * a1 + M22 * a2) * wv[k];
        }
        __builtin_nontemporal_store(r0, (f4*)(out + base + 0 * kD + j * 128 + coff));
        __builtin_nontemporal_store(r1, (f4*)(out + base + 1 * kD + j * 128 + coff));
        __builtin_nontemporal_store(r2, (f4*)(out + base + 2 * kD + j * 128 + coff));
    }
}

}  // namespace

extern "C" void kernel_launch(void* const* d_in, const int* in_sizes, int n_in,
                              void* d_out, int out_size, void* d_ws, size_t ws_size,
                              hipStream_t stream) {
    (void)n_in; (void)d_ws; (void)ws_size; (void)out_size;
    const float* in   = (const float*)d_in[0];
    const float* wght = (const float*)d_in[1];
    float* out = (float*)d_out;

    const int nrows = in_sizes[0] / (3 * kD);      // 65536
    const int rows_per_block = 256 / 32;           // 32 lanes per row -> 8 rows/block
    const int blocks = (nrows + rows_per_block - 1) / rows_per_block;

    eqln_kernel<<<blocks, 256, 0, stream>>>(in, wght, out, nrows);
}